// Round 1
// baseline (346.822 us; speedup 1.0000x reference)
//
#include <hip/hip_runtime.h>
#include <math.h>

// Problem constants (fixed by the reference: B=4, N=4096, D=3)
constexpr int B_  = 4;
constexpr int N_  = 4096;
constexpr int NV  = N_ * 3;      // 12288 flattened residual elements per (batch,dir)
constexpr int SORTN = 16384;     // next pow2 >= NV for bitonic sort

// ---------------------------------------------------------------------------
// Kernel 1: brute-force NN residuals.
// grid = (N/256, dir=2, batch=B), block = 256.
// Each block stages the full S2 point set as float4{x,y,z,|b|^2} in LDS (64KB),
// then each thread scans all 4096 candidates for its one query point.
// argmin of (|b|^2 - 2 a.b) == argmin of full squared distance (|a|^2 const).
// Strict '<' keeps the FIRST minimal index, matching jnp.argmin tie-break.
// ---------------------------------------------------------------------------
__global__ __launch_bounds__(256) void nn_resid_kernel(const float* __restrict__ x,
                                                       const float* __restrict__ y,
                                                       float* __restrict__ resid) {
    __shared__ float4 s2[N_];               // 65536 bytes
    const int b   = blockIdx.z;
    const int dir = blockIdx.y;             // 0: S1=x,S2=y ; 1: S1=y,S2=x
    const float* S1 = (dir == 0 ? x : y) + b * NV;
    const float* S2 = (dir == 0 ? y : x) + b * NV;

    for (int j = threadIdx.x; j < N_; j += 256) {
        float bx = S2[j * 3 + 0];
        float by = S2[j * 3 + 1];
        float bz = S2[j * 3 + 2];
        s2[j] = make_float4(bx, by, bz, bx * bx + by * by + bz * bz);
    }
    __syncthreads();

    const int q = blockIdx.x * 256 + threadIdx.x;
    const float ax = S1[q * 3 + 0];
    const float ay = S1[q * 3 + 1];
    const float az = S1[q * 3 + 2];

    float best = INFINITY;
    int bidx = 0;
    #pragma unroll 4
    for (int j = 0; j < N_; ++j) {
        float4 c = s2[j];                   // uniform address -> LDS broadcast
        float dot = ax * c.x + ay * c.y + az * c.z;
        float d2  = fmaf(-2.0f, dot, c.w);  // |b|^2 - 2 a.b
        if (d2 < best) { best = d2; bidx = j; }
    }

    float4 c = s2[bidx];
    float* outp = resid + (b * 2 + dir) * NV + q * 3;
    outp[0] = ax - c.x;
    outp[1] = ay - c.y;
    outp[2] = az - c.z;
}

// ---------------------------------------------------------------------------
// Kernel 2: per (batch,dir): bitonic sort of the 12288 residual values
// (padded to 16384 with +INF) in LDS, linear-interp quantiles, then two-pass
// masked mean/std.  The +INF pad region of the sort buffer is reused as
// reduction scratch so total static LDS stays at exactly 64KB.
// grid = 8, block = 1024.
// ---------------------------------------------------------------------------
__global__ __launch_bounds__(1024) void sort_stats_kernel(const float* __restrict__ resid,
                                                          float* __restrict__ stats) {
    __shared__ float buf[SORTN];            // 65536 bytes
    const int pair = blockIdx.x;            // b*2 + dir
    const int tid  = threadIdx.x;
    const float* v = resid + pair * NV;

    for (int i = tid; i < NV; i += 1024) buf[i] = v[i];
    for (int i = NV + tid; i < SORTN; i += 1024) buf[i] = INFINITY;
    __syncthreads();

    // Bitonic sort, ascending.
    for (int k = 2; k <= SORTN; k <<= 1) {
        for (int j = k >> 1; j > 0; j >>= 1) {
            for (int i = tid; i < SORTN; i += 1024) {
                int ixj = i ^ j;
                if (ixj > i) {
                    float a = buf[i];
                    float c = buf[ixj];
                    bool up = ((i & k) == 0);
                    if ((a > c) == up) { buf[i] = c; buf[ixj] = a; }
                }
            }
            __syncthreads();
        }
    }

    float* scratch = buf + NV;              // 4096 floats of dead (+INF) space

    // Quantiles (linear interpolation, positions computed in fp32 like JAX).
    if (tid == 0) {
        const float Qs[4] = {0.05f, 0.95f, 0.25f, 0.75f};
        for (int t = 0; t < 4; ++t) {
            float pos = Qs[t] * (float)(NV - 1);
            int   i0  = (int)floorf(pos);
            float fr  = pos - (float)i0;
            scratch[t] = buf[i0] + fr * (buf[i0 + 1] - buf[i0]);
        }
    }
    __syncthreads();
    const float q0 = scratch[0], q1 = scratch[1];
    const float q2 = scratch[2], q3 = scratch[3];

    // Pass 1: masked counts and sums.
    float cb = 0.f, sb = 0.f, ce = 0.f, se = 0.f;
    for (int i = tid; i < NV; i += 1024) {
        float val = buf[i];
        if ((val < q0) || (val > q1)) { cb += 1.f; sb += val; }
        if ((val > q2) && (val < q3)) { ce += 1.f; se += val; }
    }
    for (int off = 32; off > 0; off >>= 1) {
        cb += __shfl_down(cb, off);
        sb += __shfl_down(sb, off);
        ce += __shfl_down(ce, off);
        se += __shfl_down(se, off);
    }
    float* red = scratch + 8;
    const int wid = tid >> 6, lane = tid & 63;
    if (lane == 0) {
        red[wid * 4 + 0] = cb; red[wid * 4 + 1] = sb;
        red[wid * 4 + 2] = ce; red[wid * 4 + 3] = se;
    }
    __syncthreads();
    if (tid == 0) {
        float tcb = 0.f, tsb = 0.f, tce = 0.f, tse = 0.f;
        for (int w = 0; w < 16; ++w) {
            tcb += red[w * 4 + 0]; tsb += red[w * 4 + 1];
            tce += red[w * 4 + 2]; tse += red[w * 4 + 3];
        }
        scratch[4] = tsb / tcb;             // mean_begin
        scratch[5] = tse / tce;             // mean_end
        scratch[6] = tcb;                   // n_begin
        scratch[7] = tce;                   // n_end
    }
    __syncthreads();
    const float mean_b = scratch[4], mean_e = scratch[5];
    const float nb = scratch[6], ne = scratch[7];

    // Pass 2: masked sum of squared deviations.
    float vb = 0.f, ve = 0.f;
    for (int i = tid; i < NV; i += 1024) {
        float val = buf[i];
        if ((val < q0) || (val > q1)) { float d = val - mean_b; vb += d * d; }
        if ((val > q2) && (val < q3)) { float d = val - mean_e; ve += d * d; }
    }
    for (int off = 32; off > 0; off >>= 1) {
        vb += __shfl_down(vb, off);
        ve += __shfl_down(ve, off);
    }
    __syncthreads();                        // red (pass-1) fully consumed above
    if (lane == 0) { red[wid * 2 + 0] = vb; red[wid * 2 + 1] = ve; }
    __syncthreads();
    if (tid == 0) {
        float tvb = 0.f, tve = 0.f;
        for (int w = 0; w < 16; ++w) { tvb += red[w * 2 + 0]; tve += red[w * 2 + 1]; }
        stats[pair * 2 + 0] = sqrtf(tvb / (nb - 1.f));   // unbiased std, begin
        stats[pair * 2 + 1] = sqrtf(tve / (ne - 1.f));   // unbiased std, end
    }
}

// ---------------------------------------------------------------------------
// Kernel 3: per-batch max over directions, mean over batches.
// ---------------------------------------------------------------------------
__global__ void final_kernel(const float* __restrict__ stats, float* __restrict__ out) {
    if (threadIdx.x == 0 && blockIdx.x == 0) {
        float sb = 0.f, se = 0.f;
        for (int b = 0; b < B_; ++b) {
            float b1 = stats[(b * 2 + 0) * 2 + 0];
            float b2 = stats[(b * 2 + 1) * 2 + 0];
            float e1 = stats[(b * 2 + 0) * 2 + 1];
            float e2 = stats[(b * 2 + 1) * 2 + 1];
            sb += fmaxf(b1, b2);
            se += fmaxf(e1, e2);
        }
        out[0] = sb / (float)B_;
        out[1] = se / (float)B_;
    }
}

extern "C" void kernel_launch(void* const* d_in, const int* in_sizes, int n_in,
                              void* d_out, int out_size, void* d_ws, size_t ws_size,
                              hipStream_t stream) {
    const float* x = (const float*)d_in[0];
    const float* y = (const float*)d_in[1];
    float* out = (float*)d_out;

    float* resid = (float*)d_ws;                     // B*2*NV floats = 393KB
    float* stats = resid + B_ * 2 * NV;              // 16 floats

    dim3 gridA(N_ / 256, 2, B_);
    nn_resid_kernel<<<gridA, 256, 0, stream>>>(x, y, resid);
    sort_stats_kernel<<<B_ * 2, 1024, 0, stream>>>(resid, stats);
    final_kernel<<<1, 64, 0, stream>>>(stats, out);
}

// Round 2
// 73.410 us; speedup vs baseline: 4.7245x; 4.7245x over previous
//
#include <hip/hip_runtime.h>
#include <math.h>

// Problem constants (fixed by the reference: B=4, N=4096, D=3)
constexpr int B_  = 4;
constexpr int N_  = 4096;
constexpr int NV  = N_ * 3;      // 12288 flattened residual elements per (batch,dir)
constexpr int CCHUNK = 1024;     // candidates per chunk (4 chunks)
constexpr int NCH = N_ / CCHUNK; // 4

// float <-> monotonic uint key (order-preserving for all finite floats)
__device__ inline unsigned f2k(float f) {
    unsigned b = __float_as_uint(f);
    return b ^ ((unsigned)((int)b >> 31) | 0x80000000u);
}
__device__ inline float k2f(unsigned k) {
    unsigned b = (k & 0x80000000u) ? (k ^ 0x80000000u) : ~k;
    return __uint_as_float(b);
}

// ---------------------------------------------------------------------------
// Kernel 1a: partial NN over a 1024-candidate chunk.
// grid = (N/256 query chunks, NCH cand chunks, 8 pairs), block = 256.
// Writes (best_d2, best_idx) per (pair, cand-chunk, query).
// d2 = |b|^2 - 2 a.b (|a|^2 dropped: constant per query, argmin-invariant).
// ---------------------------------------------------------------------------
__global__ __launch_bounds__(256) void nn_partial_kernel(const float* __restrict__ x,
                                                         const float* __restrict__ y,
                                                         float2* __restrict__ part) {
    __shared__ float4 s2[CCHUNK];           // 16 KB
    const int pair = blockIdx.z;
    const int b    = pair >> 1;
    const int dir  = pair & 1;              // 0: S1=x,S2=y ; 1: S1=y,S2=x
    const float* S1 = (dir == 0 ? x : y) + b * NV;
    const float* S2 = (dir == 0 ? y : x) + b * NV;
    const int cbase = blockIdx.y * CCHUNK;

    for (int j = threadIdx.x; j < CCHUNK; j += 256) {
        float bx = S2[(cbase + j) * 3 + 0];
        float by = S2[(cbase + j) * 3 + 1];
        float bz = S2[(cbase + j) * 3 + 2];
        s2[j] = make_float4(bx, by, bz, bx * bx + by * by + bz * bz);
    }
    __syncthreads();

    const int q = blockIdx.x * 256 + threadIdx.x;
    const float ax = S1[q * 3 + 0];
    const float ay = S1[q * 3 + 1];
    const float az = S1[q * 3 + 2];

    float best = INFINITY;
    int bidx = 0;
    #pragma unroll 8
    for (int j = 0; j < CCHUNK; ++j) {
        float4 c = s2[j];                   // uniform address -> LDS broadcast
        float dot = ax * c.x + ay * c.y + az * c.z;
        float d2  = fmaf(-2.0f, dot, c.w);
        if (d2 < best) { best = d2; bidx = cbase + j; }
    }
    part[(pair * NCH + blockIdx.y) * N_ + q] = make_float2(best, (float)bidx);
}

// ---------------------------------------------------------------------------
// Kernel 1b: merge the NCH partials per query (ascending chunk order + strict
// '<' == global first-index argmin), gather S2[idx], write residuals.
// grid = (N/256, 8 pairs), block = 256.
// ---------------------------------------------------------------------------
__global__ __launch_bounds__(256) void nn_merge_kernel(const float* __restrict__ x,
                                                       const float* __restrict__ y,
                                                       const float2* __restrict__ part,
                                                       float* __restrict__ resid) {
    const int pair = blockIdx.y;
    const int b    = pair >> 1;
    const int dir  = pair & 1;
    const float* S1 = (dir == 0 ? x : y) + b * NV;
    const float* S2 = (dir == 0 ? y : x) + b * NV;
    const int q = blockIdx.x * 256 + threadIdx.x;

    float best = INFINITY;
    int bidx = 0;
    #pragma unroll
    for (int c = 0; c < NCH; ++c) {
        float2 p = part[(pair * NCH + c) * N_ + q];
        if (p.x < best) { best = p.x; bidx = (int)p.y; }
    }
    float* outp = resid + pair * NV + q * 3;
    outp[0] = S1[q * 3 + 0] - S2[bidx * 3 + 0];
    outp[1] = S1[q * 3 + 1] - S2[bidx * 3 + 1];
    outp[2] = S1[q * 3 + 2] - S2[bidx * 3 + 2];
}

// ---------------------------------------------------------------------------
// Kernel 2: exact quantile via MSD radix select (4 x 8-bit passes in LDS).
// grid = 32 (pair*4 + quantile_idx), block = 1024.
// Selects order stats k0 and k0+1, writes linear-interp quantile to qbuf.
// ---------------------------------------------------------------------------
__global__ __launch_bounds__(1024) void quantile_select_kernel(const float* __restrict__ resid,
                                                               float* __restrict__ qbuf) {
    __shared__ unsigned keys[NV];           // 48 KB
    __shared__ int hist[256];
    __shared__ int s_sel, s_want, s_cnt;
    __shared__ unsigned s_min;

    const int t    = blockIdx.x & 3;        // quantile index
    const int pair = blockIdx.x >> 2;
    const int tid  = threadIdx.x;
    const float* v = resid + pair * NV;

    const float Qs[4] = {0.05f, 0.95f, 0.25f, 0.75f};
    const float pos = Qs[t] * (float)(NV - 1);   // fp32, matches jnp.quantile
    const int   k0  = (int)floorf(pos);
    const float fr  = pos - (float)k0;

    for (int i = tid; i < NV; i += 1024) keys[i] = f2k(v[i]);
    __syncthreads();

    // MSD radix select for the k0-th smallest (0-based).
    unsigned prefix = 0u, pmask = 0u;
    int want = k0;
    for (int shift = 24; shift >= 0; shift -= 8) {
        for (int i = tid; i < 256; i += 1024) hist[i] = 0;
        __syncthreads();
        for (int i = tid; i < NV; i += 1024) {
            unsigned k = keys[i];
            if ((k & pmask) == prefix) atomicAdd(&hist[(k >> shift) & 255], 1);
        }
        __syncthreads();
        if (tid < 64) {                     // wave-parallel 256-bin scan
            int c0 = hist[tid * 4 + 0], c1 = hist[tid * 4 + 1];
            int c2 = hist[tid * 4 + 2], c3 = hist[tid * 4 + 3];
            int s = c0 + c1 + c2 + c3;
            int pre = s;
            #pragma unroll
            for (int off = 1; off < 64; off <<= 1) {
                int u = __shfl_up(pre, off);
                if (tid >= off) pre += u;
            }
            int excl = pre - s;             // count in lanes before this one
            bool hit = (want >= excl) && (want < excl + s);
            unsigned long long m = __ballot(hit);
            int hl = (int)(__ffsll((unsigned long long)m) - 1);
            if (tid == hl) {
                int w = want - excl;
                int sel;
                if      (w < c0)           { sel = tid * 4 + 0; }
                else if (w < c0 + c1)      { sel = tid * 4 + 1; w -= c0; }
                else if (w < c0 + c1 + c2) { sel = tid * 4 + 2; w -= c0 + c1; }
                else                       { sel = tid * 4 + 3; w -= c0 + c1 + c2; }
                s_sel = sel; s_want = w;
            }
        }
        __syncthreads();
        prefix |= ((unsigned)s_sel) << shift;
        pmask  |= (0xFFu << shift);
        want = s_want;
        __syncthreads();
    }
    const unsigned key0 = prefix;           // exact k0-th smallest key
    const float v0 = k2f(key0);

    // (k0+1)-th order stat: duplicate-aware.
    if (tid == 0) { s_cnt = 0; s_min = 0xFFFFFFFFu; }
    __syncthreads();
    int loc = 0; unsigned locmin = 0xFFFFFFFFu;
    for (int i = tid; i < NV; i += 1024) {
        unsigned k = keys[i];
        if (k <= key0) loc++;
        else if (k < locmin) locmin = k;
    }
    atomicAdd(&s_cnt, loc);
    atomicMin(&s_min, locmin);
    __syncthreads();
    if (tid == 0) {
        float v1 = (s_cnt >= k0 + 2) ? v0 : k2f(s_min);
        qbuf[pair * 4 + t] = v0 + fr * (v1 - v0);
    }
}

// ---------------------------------------------------------------------------
// Kernel 3: masked two-pass mean/std per pair. grid = 8, block = 1024.
// ---------------------------------------------------------------------------
__global__ __launch_bounds__(1024) void masked_stats_kernel(const float* __restrict__ resid,
                                                            const float* __restrict__ qbuf,
                                                            float* __restrict__ stats) {
    __shared__ float red[64];
    __shared__ float sh[8];
    const int pair = blockIdx.x;
    const int tid  = threadIdx.x;
    const float* v = resid + pair * NV;
    const float q0 = qbuf[pair * 4 + 0], q1 = qbuf[pair * 4 + 1];
    const float q2 = qbuf[pair * 4 + 2], q3 = qbuf[pair * 4 + 3];

    // Pass 1: masked counts and sums.
    float cb = 0.f, sb = 0.f, ce = 0.f, se = 0.f;
    for (int i = tid; i < NV; i += 1024) {
        float val = v[i];
        if ((val < q0) || (val > q1)) { cb += 1.f; sb += val; }
        if ((val > q2) && (val < q3)) { ce += 1.f; se += val; }
    }
    for (int off = 32; off > 0; off >>= 1) {
        cb += __shfl_down(cb, off);
        sb += __shfl_down(sb, off);
        ce += __shfl_down(ce, off);
        se += __shfl_down(se, off);
    }
    const int wid = tid >> 6, lane = tid & 63;
    if (lane == 0) {
        red[wid * 4 + 0] = cb; red[wid * 4 + 1] = sb;
        red[wid * 4 + 2] = ce; red[wid * 4 + 3] = se;
    }
    __syncthreads();
    if (tid == 0) {
        float tcb = 0.f, tsb = 0.f, tce = 0.f, tse = 0.f;
        for (int w = 0; w < 16; ++w) {
            tcb += red[w * 4 + 0]; tsb += red[w * 4 + 1];
            tce += red[w * 4 + 2]; tse += red[w * 4 + 3];
        }
        sh[0] = tsb / tcb;                  // mean_begin
        sh[1] = tse / tce;                  // mean_end
        sh[2] = tcb;                        // n_begin
        sh[3] = tce;                        // n_end
    }
    __syncthreads();
    const float mean_b = sh[0], mean_e = sh[1];
    const float nb = sh[2], ne = sh[3];

    // Pass 2: masked sum of squared deviations.
    float vb = 0.f, ve = 0.f;
    for (int i = tid; i < NV; i += 1024) {
        float val = v[i];
        if ((val < q0) || (val > q1)) { float d = val - mean_b; vb += d * d; }
        if ((val > q2) && (val < q3)) { float d = val - mean_e; ve += d * d; }
    }
    for (int off = 32; off > 0; off >>= 1) {
        vb += __shfl_down(vb, off);
        ve += __shfl_down(ve, off);
    }
    __syncthreads();
    if (lane == 0) { red[wid * 2 + 0] = vb; red[wid * 2 + 1] = ve; }
    __syncthreads();
    if (tid == 0) {
        float tvb = 0.f, tve = 0.f;
        for (int w = 0; w < 16; ++w) { tvb += red[w * 2 + 0]; tve += red[w * 2 + 1]; }
        stats[pair * 2 + 0] = sqrtf(tvb / (nb - 1.f));   // unbiased std, begin
        stats[pair * 2 + 1] = sqrtf(tve / (ne - 1.f));   // unbiased std, end
    }
}

// ---------------------------------------------------------------------------
// Kernel 4: per-batch max over directions, mean over batches.
// ---------------------------------------------------------------------------
__global__ void final_kernel(const float* __restrict__ stats, float* __restrict__ out) {
    if (threadIdx.x == 0 && blockIdx.x == 0) {
        float sb = 0.f, se = 0.f;
        for (int b = 0; b < B_; ++b) {
            float b1 = stats[(b * 2 + 0) * 2 + 0];
            float b2 = stats[(b * 2 + 1) * 2 + 0];
            float e1 = stats[(b * 2 + 0) * 2 + 1];
            float e2 = stats[(b * 2 + 1) * 2 + 1];
            sb += fmaxf(b1, b2);
            se += fmaxf(e1, e2);
        }
        out[0] = sb / (float)B_;
        out[1] = se / (float)B_;
    }
}

extern "C" void kernel_launch(void* const* d_in, const int* in_sizes, int n_in,
                              void* d_out, int out_size, void* d_ws, size_t ws_size,
                              hipStream_t stream) {
    const float* x = (const float*)d_in[0];
    const float* y = (const float*)d_in[1];
    float* out = (float*)d_out;

    float*  resid = (float*)d_ws;                        // 8*NV floats = 384 KB
    float2* part  = (float2*)(resid + 8 * NV);           // 8*4*4096 float2 = 1 MB
    float*  qbuf  = (float*)(part + 8 * NCH * N_);       // 32 floats
    float*  stats = qbuf + 32;                           // 16 floats

    nn_partial_kernel<<<dim3(N_ / 256, NCH, 8), 256, 0, stream>>>(x, y, part);
    nn_merge_kernel<<<dim3(N_ / 256, 8), 256, 0, stream>>>(x, y, part, resid);
    quantile_select_kernel<<<32, 1024, 0, stream>>>(resid, qbuf);
    masked_stats_kernel<<<8, 1024, 0, stream>>>(resid, qbuf, stats);
    final_kernel<<<1, 64, 0, stream>>>(stats, out);
}